// Round 10
// baseline (432.907 us; speedup 1.0000x reference)
//
#include <hip/hip_runtime.h>
#include <stdint.h>

// Problem: B=2, S=2048, D=1024, H=16, dh=64
// Inputs fp32, OUTPUT fp32. Internals bf16 (threshold has bf16 floor).
#define SEQ    2048
#define DMODEL 1024

typedef __bf16 bf16x8 __attribute__((ext_vector_type(8)));
typedef float  f32x4  __attribute__((ext_vector_type(4)));

typedef __attribute__((address_space(1))) const void CGV;  // global
typedef __attribute__((address_space(3))) void LDSV;       // LDS

__device__ __forceinline__ void load_lds16(const void* g, void* l) {
    __builtin_amdgcn_global_load_lds((CGV*)g, (LDSV*)l, 16, 0, 0);
}

// ---------------------------------------------------------------------------
// Transpose+convert: in f32 [R][C] -> out bf16 [C][R].  grid (C/32, R/32), 256
// ---------------------------------------------------------------------------
__global__ __launch_bounds__(256)
void transpose_f32_to_bf16(const float* __restrict__ in, __bf16* __restrict__ out,
                           int R, int C)
{
    __shared__ float tile[32][33];
    const int t  = threadIdx.x;
    const int tx = t & 31, ty = t >> 5;
    const int c0 = blockIdx.x * 32;
    const int r0 = blockIdx.y * 32;
#pragma unroll
    for (int i = 0; i < 4; ++i)
        tile[ty + i * 8][tx] = in[(size_t)(r0 + ty + i * 8) * C + c0 + tx];
    __syncthreads();
#pragma unroll
    for (int i = 0; i < 4; ++i)
        out[(size_t)(c0 + ty + i * 8) * R + r0 + tx] = (__bf16)tile[tx][ty + i * 8];
}

// ---------------------------------------------------------------------------
// V transpose (bf16): in [32][2048][64] -> out [32][64][2048]
// grid (SEQ/32, 64/32, 32), 256 thr
// ---------------------------------------------------------------------------
__global__ __launch_bounds__(256)
void transpose_v(const __bf16* __restrict__ in, __bf16* __restrict__ out)
{
    __shared__ __bf16 tile[32][34];
    const int t  = threadIdx.x;
    const int tx = t & 31, ty = t >> 5;
    const int s0 = blockIdx.x * 32;
    const int d0 = blockIdx.y * 32;
    const int bh = blockIdx.z;
    const __bf16* ip = in  + (size_t)bh * SEQ * 64;
    __bf16*       op = out + (size_t)bh * 64 * SEQ;
#pragma unroll
    for (int i = 0; i < 4; ++i)
        tile[ty + i * 8][tx] = ip[(size_t)(s0 + ty + i * 8) * 64 + d0 + tx];
    __syncthreads();
#pragma unroll
    for (int i = 0; i < 4; ++i)
        op[(size_t)(d0 + ty + i * 8) * SEQ + s0 + tx] = tile[tx][ty + i * 8];
}

// ---------------------------------------------------------------------------
// GEMM (m97 structure): C[M x NTILE-grid] = A[M x K] @ Bt[N x K]^T + bias[N]
// NTILE = 128 (GEMM1) or 64 (GEMM2, more blocks -> better occupancy).
// mode 0: scatter bf16 Q/K/V row-major [B,H,S,dh];  mode 1: fp32 row-major
// ---------------------------------------------------------------------------
template<bool A_IS_F32, int NTILE>
__global__ __launch_bounds__(256)
void gemm_kernel(const void* __restrict__ Av, const __bf16* __restrict__ Bt,
                 const float* __restrict__ bias,
                 __bf16* __restrict__ Cq, __bf16* __restrict__ Ck,
                 __bf16* __restrict__ Cv, float* __restrict__ Cplain,
                 int K, int N, int mode)
{
    constexpr int NI = NTILE / 32;                 // ni-blocks per wave (4 or 2)
    __shared__ __attribute__((aligned(16))) __bf16 As[128][32];
    __shared__ __attribute__((aligned(16))) __bf16 Bs[NTILE][32];

    const int t    = threadIdx.x;
    const int wave = __builtin_amdgcn_readfirstlane(t >> 6);
    const int lane = t & 63;
    const int l15  = lane & 15;
    const int quad = lane >> 4;
    const int wm   = (wave >> 1) * 64;
    const int wn   = (wave & 1) * (NTILE / 2);
    const int m0   = blockIdx.y * 128;
    const int n0   = blockIdx.x * NTILE;

    const int arow  = lane >> 2;
    const int akoff = (lane & 3) * 8;

    f32x4 acc[4][NI] = {};

    for (int k0 = 0; k0 < K; k0 += 32) {
        __syncthreads();
        if (A_IS_F32) {
            const float* A = (const float*)Av;
            int row = t >> 1, kk = (t & 1) * 16;
            const float* srcp = A + (size_t)(m0 + row) * K + k0 + kk;
            float4 v0 = *(const float4*)(srcp);
            float4 v1 = *(const float4*)(srcp + 4);
            float4 v2 = *(const float4*)(srcp + 8);
            float4 v3 = *(const float4*)(srcp + 12);
            __bf16 tmp[16] = {
                (__bf16)v0.x, (__bf16)v0.y, (__bf16)v0.z, (__bf16)v0.w,
                (__bf16)v1.x, (__bf16)v1.y, (__bf16)v1.z, (__bf16)v1.w,
                (__bf16)v2.x, (__bf16)v2.y, (__bf16)v2.z, (__bf16)v2.w,
                (__bf16)v3.x, (__bf16)v3.y, (__bf16)v3.z, (__bf16)v3.w };
            *(uint4*)(&As[row][kk])     = *(uint4*)(tmp);
            *(uint4*)(&As[row][kk + 8]) = *(uint4*)(tmp + 8);
        } else {
            const __bf16* A = (const __bf16*)Av;
#pragma unroll
            for (int p = 0; p < 2; ++p) {
                int slab = (wave * 2 + p) * 16;
                const __bf16* g = A + (size_t)(m0 + slab + arow) * K + k0 + akoff;
                load_lds16(g, &As[slab][0]);
            }
        }
        // B staging: NTILE rows / 16-row slabs, spread over 4 waves
#pragma unroll
        for (int p = 0; p < NTILE / 64; ++p) {
            int slab = (wave * (NTILE / 64) + p) * 16;
            const __bf16* g = Bt + (size_t)(n0 + slab + arow) * K + k0 + akoff;
            load_lds16(g, &Bs[slab][0]);
        }
        __syncthreads();

        bf16x8 af[4], bfr[NI];
#pragma unroll
        for (int mi = 0; mi < 4; ++mi)
            af[mi] = *(const bf16x8*)(&As[wm + mi * 16 + l15][quad * 8]);
#pragma unroll
        for (int ni = 0; ni < NI; ++ni)
            bfr[ni] = *(const bf16x8*)(&Bs[wn + ni * 16 + l15][quad * 8]);
#pragma unroll
        for (int mi = 0; mi < 4; ++mi)
#pragma unroll
            for (int ni = 0; ni < NI; ++ni)
                acc[mi][ni] = __builtin_amdgcn_mfma_f32_16x16x32_bf16(
                    af[mi], bfr[ni], acc[mi][ni], 0, 0, 0);
    }

#pragma unroll
    for (int mi = 0; mi < 4; ++mi) {
        int rowb = m0 + wm + mi * 16 + quad * 4;
#pragma unroll
        for (int ni = 0; ni < NI; ++ni) {
            int col = n0 + wn + ni * 16 + l15;
            float bia = bias[col];
#pragma unroll
            for (int r = 0; r < 4; ++r) {
                float v = acc[mi][ni][r] + bia;
                int rr = rowb + r;
                if (mode == 0) {
                    int b = rr >> 11;
                    int s = rr & 2047;
                    int part = col >> 10;
                    int rem  = col & 1023;
                    int h = rem >> 6;
                    int d = rem & 63;
                    __bf16* dst = (part == 0) ? Cq : (part == 1) ? Ck : Cv;
                    dst[(((size_t)(b * 16 + h)) * SEQ + s) * 64 + d] = (__bf16)v;
                } else {
                    Cplain[(size_t)rr * N + col] = v;
                }
            }
        }
    }
}

// ---------------------------------------------------------------------------
// MFMA flash attention, widened: 128-thread blocks (2 waves), 64 q-rows/block,
// 32 q-rows per wave (2 subtiles u=0,1). S^T formulation (R8-verified math),
// R6-proven 2-barrier structure, direct global loads (no cross-barrier
// register pipeline -- R7/R9 lessons). K fragments shared across subtiles.
// grid (B*H=32, S/64=32) = 1024 blocks -> 8 blocks/CU, 16 waves/CU.
// ---------------------------------------------------------------------------
__global__ __launch_bounds__(128, 4)
void attn_kernel(const __bf16* __restrict__ Q, const __bf16* __restrict__ Kb,
                 const __bf16* __restrict__ Vtg, const float* __restrict__ mask,
                 __bf16* __restrict__ Out)
{
    __shared__ __attribute__((aligned(16))) __bf16 Vt[64][72];        // [d][key]
    __shared__ __attribute__((aligned(16))) __bf16 Ps[2][2][16][72];  // [wave][u][q][key]

    const int t    = threadIdx.x;       // 0..127
    const int wave = t >> 6;            // 0..1
    const int lane = t & 63;
    const int l15  = lane & 15;
    const int quad = lane >> 4;
    const int bh   = blockIdx.x;
    const int b    = bh >> 4;
    const int h    = bh & 15;
    const int bq0  = blockIdx.y * 64;

    const __bf16* Qp  = Q   + (size_t)bh * SEQ * 64;
    const __bf16* Kp  = Kb  + (size_t)bh * SEQ * 64;
    const __bf16* Vtp = Vtg + (size_t)bh * 64 * SEQ;   // [d][s]

    // subtile q bases: u=0 -> bq0+wave*16, u=1 -> +32
    int qbase[2];
    qbase[0] = bq0 + wave * 16;
    qbase[1] = bq0 + 32 + wave * 16;

    const float* Mpu[2];
#pragma unroll
    for (int u = 0; u < 2; ++u)
        Mpu[u] = mask + (size_t)b * SEQ * SEQ + (size_t)(qbase[u] + l15) * SEQ;

    // Q fragments (B-operand for S^T): lane q=l15, k=quad*8..
    bf16x8 qf[2][2];
#pragma unroll
    for (int u = 0; u < 2; ++u)
#pragma unroll
        for (int ks = 0; ks < 2; ++ks)
            qf[u][ks] = *(const bf16x8*)(Qp + (size_t)(qbase[u] + l15) * 64 + ks * 32 + quad * 8);

    // V staging mapping: thread covers row d = t>>1, half (t&1)*32, 4 chunks
    const int vd = t >> 1;
    const int vh = (t & 1) * 32;

    f32x4 oacc[2][4] = {};
    float mrun[2] = { -1e30f, -1e30f };
    float lrun[2] = { 0.f, 0.f };

    for (int kt = 0; kt < SEQ / 64; ++kt) {
        const int key0 = kt * 64;
        __syncthreads();                           // WAR: prev consumers done
        // ---- stage V^T tile (4 x 16B per thread, direct global->reg->LDS) ----
#pragma unroll
        for (int c = 0; c < 4; ++c) {
            int ky = vh + c * 8;
            *(uint4*)(&Vt[vd][ky]) = *(const uint4*)(Vtp + (size_t)vd * SEQ + key0 + ky);
        }
        // ---- S^T = K Q^T ; K frags shared across u; fold mask immediately ----
        float s[2][4][4];
#pragma unroll
        for (int nb = 0; nb < 4; ++nb) {
            const __bf16* kp = Kp + (size_t)(key0 + nb * 16 + l15) * 64;
            bf16x8 kf0 = *(const bf16x8*)(kp + quad * 8);
            bf16x8 kf1 = *(const bf16x8*)(kp + 32 + quad * 8);
#pragma unroll
            for (int u = 0; u < 2; ++u) {
                f32x4 z = {};
                z = __builtin_amdgcn_mfma_f32_16x16x32_bf16(kf0, qf[u][0], z, 0, 0, 0);
                z = __builtin_amdgcn_mfma_f32_16x16x32_bf16(kf1, qf[u][1], z, 0, 0, 0);
                float4 mq = *(const float4*)(Mpu[u] + key0 + nb * 16 + quad * 4);
                s[u][nb][0] = z[0] * 0.125f * mq.x + (mq.x - 1.0f) * 10000.0f;
                s[u][nb][1] = z[1] * 0.125f * mq.y + (mq.y - 1.0f) * 10000.0f;
                s[u][nb][2] = z[2] * 0.125f * mq.z + (mq.z - 1.0f) * 10000.0f;
                s[u][nb][3] = z[3] * 0.125f * mq.w + (mq.w - 1.0f) * 10000.0f;
            }
        }
        __syncthreads();                           // RAW: Vt visible

        // ---- softmax per subtile (q=l15): in-lane 16 + 2 cross-quad shfls ----
        float alpha[2];
#pragma unroll
        for (int u = 0; u < 2; ++u) {
            float vmax = s[u][0][0];
#pragma unroll
            for (int nb = 0; nb < 4; ++nb)
#pragma unroll
                for (int r = 0; r < 4; ++r) vmax = fmaxf(vmax, s[u][nb][r]);
            vmax = fmaxf(vmax, __shfl_xor(vmax, 16));
            vmax = fmaxf(vmax, __shfl_xor(vmax, 32));
            float mnew = fmaxf(mrun[u], vmax);
            alpha[u] = __expf(mrun[u] - mnew);
            mrun[u] = mnew;
            float psum = 0.f;
#pragma unroll
            for (int nb = 0; nb < 4; ++nb)
#pragma unroll
                for (int r = 0; r < 4; ++r) {
                    float p = __expf(s[u][nb][r] - mnew);
                    s[u][nb][r] = p;
                    psum += p;
                }
            psum += __shfl_xor(psum, 16);
            psum += __shfl_xor(psum, 32);
            lrun[u] = lrun[u] * alpha[u] + psum;
            // P store (wave-private; lgkm ordering, no barrier)
#pragma unroll
            for (int nb = 0; nb < 4; ++nb) {
                __bf16 pk[4] = { (__bf16)s[u][nb][0], (__bf16)s[u][nb][1],
                                 (__bf16)s[u][nb][2], (__bf16)s[u][nb][3] };
                *(uint2*)(&Ps[wave][u][l15][nb * 16 + quad * 4]) = *(uint2*)pk;
            }
        }
        // ---- O rescale ----
#pragma unroll
        for (int u = 0; u < 2; ++u) {
            float ar[4];
#pragma unroll
            for (int r = 0; r < 4; ++r)
                ar[r] = __shfl(alpha[u], quad * 4 + r);
#pragma unroll
            for (int cb = 0; cb < 4; ++cb)
#pragma unroll
                for (int r = 0; r < 4; ++r)
                    oacc[u][cb][r] *= ar[r];
        }
        // ---- O += P V ; vf shared across u ----
        bf16x8 pf[2][2];
#pragma unroll
        for (int u = 0; u < 2; ++u)
#pragma unroll
            for (int ks = 0; ks < 2; ++ks)
                pf[u][ks] = *(const bf16x8*)(&Ps[wave][u][l15][ks * 32 + quad * 8]);
#pragma unroll
        for (int cb = 0; cb < 4; ++cb) {
#pragma unroll
            for (int ks = 0; ks < 2; ++ks) {
                bf16x8 vf = *(const bf16x8*)(&Vt[cb * 16 + l15][ks * 32 + quad * 8]);
#pragma unroll
                for (int u = 0; u < 2; ++u)
                    oacc[u][cb] = __builtin_amdgcn_mfma_f32_16x16x32_bf16(
                        pf[u][ks], vf, oacc[u][cb], 0, 0, 0);
            }
        }
    }
    // epilogue: row q = quad*4+r, col d = cb*16+l15
#pragma unroll
    for (int u = 0; u < 2; ++u) {
        float lr[4];
#pragma unroll
        for (int r = 0; r < 4; ++r)
            lr[r] = __shfl(lrun[u], quad * 4 + r);
#pragma unroll
        for (int cb = 0; cb < 4; ++cb) {
#pragma unroll
            for (int r = 0; r < 4; ++r) {
                int qq = qbase[u] + quad * 4 + r;
                float v = oacc[u][cb][r] / lr[r];
                Out[((size_t)(b * SEQ + qq)) * DMODEL + h * 64 + cb * 16 + l15] = (__bf16)v;
            }
        }
    }
}

// ---------------------------------------------------------------------------
extern "C" void kernel_launch(void* const* d_in, const int* in_sizes, int n_in,
                              void* d_out, int out_size, void* d_ws, size_t ws_size,
                              hipStream_t stream)
{
    const float* src  = nullptr;  // 4194304
    const float* mask = nullptr;  // 8388608
    const float* Wqkv = nullptr;  // 3145728
    const float* bqkv = nullptr;  // 3072
    const float* Wout = nullptr;  // 1048576
    const float* bout = nullptr;  // 1024
    for (int i = 0; i < n_in; ++i) {
        switch (in_sizes[i]) {
            case 4194304: src  = (const float*)d_in[i]; break;
            case 8388608: mask = (const float*)d_in[i]; break;
            case 3145728: Wqkv = (const float*)d_in[i]; break;
            case 3072:    bqkv = (const float*)d_in[i]; break;
            case 1048576: Wout = (const float*)d_in[i]; break;
            case 1024:    bout = (const float*)d_in[i]; break;
        }
    }
    float* out = (float*)d_out;                  // [2,2048,1024] fp32

    const size_t NE = (size_t)2 * 16 * SEQ * 64; // 4M elems
    __bf16* Qb     = (__bf16*)d_ws;              // 4M
    __bf16* Kb     = Qb + NE;                    // 4M
    __bf16* Vb     = Kb + NE;                    // 4M (dead after transpose_v)
    __bf16* Vtg    = Vb + NE;                    // 4M  [bh][d][s]
    __bf16* Wqkv_t = Vtg + NE;                   // 3M  [3072][1024]
    __bf16* Wout_t = Wqkv_t + (size_t)3072 * 1024; // 1M [1024][1024]
    __bf16* Ao     = Vb;                         // alias: Vb dead by then

    transpose_f32_to_bf16<<<dim3(3072 / 32, 1024 / 32), 256, 0, stream>>>(
        Wqkv, Wqkv_t, 1024, 3072);
    transpose_f32_to_bf16<<<dim3(1024 / 32, 1024 / 32), 256, 0, stream>>>(
        Wout, Wout_t, 1024, 1024);

    gemm_kernel<true, 128><<<dim3(3072 / 128, 4096 / 128), 256, 0, stream>>>(
        (const void*)src, Wqkv_t, bqkv, Qb, Kb, Vb, nullptr, 1024, 3072, 0);

    transpose_v<<<dim3(SEQ / 32, 2, 32), 256, 0, stream>>>(Vb, Vtg);

    attn_kernel<<<dim3(32, SEQ / 64), 128, 0, stream>>>(Qb, Kb, Vtg, mask, Ao);

    // GEMM2: 128x64 tiles -> 512 blocks (2/CU, 8 waves/CU)
    gemm_kernel<false, 64><<<dim3(1024 / 64, 4096 / 128), 256, 0, stream>>>(
        (const void*)Ao, Wout_t, bout, nullptr, nullptr, nullptr, out, 1024, 1024, 1);
}